// Round 6
// baseline (5753.093 us; speedup 1.0000x reference)
//
#include <hip/hip_runtime.h>

#define NT 512   // 8 waves: wave q owns sample q for ACT/head; GEMV role = (gate g=q&3, k-half kh=q>>2)

#if __has_builtin(__builtin_amdgcn_exp2f)
__device__ __forceinline__ float fexp(float x) { return __builtin_amdgcn_exp2f(x * 1.4426950408889634f); }
#else
__device__ __forceinline__ float fexp(float x) { return __expf(x); }
#endif
#if __has_builtin(__builtin_amdgcn_rcpf)
__device__ __forceinline__ float frcp(float x) { return __builtin_amdgcn_rcpf(x); }
#else
__device__ __forceinline__ float frcp(float x) { return 1.0f / x; }
#endif

__device__ __forceinline__ float sigm(float x)  { return frcp(1.0f + fexp(-x)); }
__device__ __forceinline__ float tanh_(float x) { return 1.0f - 2.0f * frcp(1.0f + fexp(2.0f * x)); }
__device__ __forceinline__ float lrelu(float x) { return x > 0.0f ? x : 0.01f * x; }

__global__ __launch_bounds__(NT, 1)
void gen_kernel(
    const float* __restrict__ noise,
    const float* __restrict__ w_ih0, const float* __restrict__ w_hh0,
    const float* __restrict__ b_ih0, const float* __restrict__ b_hh0,
    const float* __restrict__ w_ih1, const float* __restrict__ w_hh1,
    const float* __restrict__ b_ih1, const float* __restrict__ b_hh1,
    const float* __restrict__ w_ih2, const float* __restrict__ w_hh2,
    const float* __restrict__ b_ih2, const float* __restrict__ b_hh2,
    const float* __restrict__ fc1_w, const float* __restrict__ fc1_b,
    const float* __restrict__ fc2_w, const float* __restrict__ fc2_b,
    const float* __restrict__ fc3_w, const float* __restrict__ fc3_b,
    const int*   __restrict__ flow_len_p,
    float* __restrict__ out)
{
    // [sample][gate][k-half][unit] single-float partials (16 KB)
    __shared__ float s_part[8][4][2][64];
    __shared__ float s_h[3][8][64] __attribute__((aligned(16)));   // 6 KB

    const int tid  = threadIdx.x;
    const int j    = tid & 63;      // unit / lane
    const int q    = tid >> 6;      // wave = ACT/head sample
    const int g    = q & 3;         // GEMV gate role
    const int kh   = q >> 2;        // GEMV k-half role (0/1)
    const int koff = kh * 32;
    const int base = blockIdx.x * 8;
    const int T    = flow_len_p[0];

    // ---- register-stationary weights: row g*64+j, cols [koff, koff+32) ----
    float wh0r[32], wi1r[32], wh1r[32], wi2r[32], wh2r[32];
    {
        const int r = g * 64 + j;
#define LW(dst, src)                                                          \
        { const float4* p4 = (const float4*)((src) + r * 64 + koff);          \
          _Pragma("unroll")                                                   \
          for (int i = 0; i < 8; ++i) { float4 v = p4[i];                     \
            (dst)[4*i+0]=v.x; (dst)[4*i+1]=v.y; (dst)[4*i+2]=v.z; (dst)[4*i+3]=v.w; } }
        LW(wh0r, w_hh0) LW(wi1r, w_ih1) LW(wh1r, w_hh1) LW(wi2r, w_ih2) LW(wh2r, w_hh2)
    }
    float wi0[4][3], rb0[4], rb1v[4], rb2v[4];   // ACT data for (sample q, unit j)
#pragma unroll
    for (int gg = 0; gg < 4; ++gg) {
        const int r = gg * 64 + j;
        wi0[gg][0] = w_ih0[r*3+0]; wi0[gg][1] = w_ih0[r*3+1]; wi0[gg][2] = w_ih0[r*3+2];
        rb0[gg]  = b_ih0[r] + b_hh0[r];
        rb1v[gg] = b_ih1[r] + b_hh1[r];
        rb2v[gg] = b_ih2[r] + b_hh2[r];
    }
    // ---- head weights (wave-local shuffle head) ----
    const int o1 = j & 31, hf = j >> 5;
    float wfc1[32];
#pragma unroll
    for (int i = 0; i < 8; ++i) {
        float4 v = ((const float4*)(fc1_w + o1 * 64 + hf * 32))[i];
        wfc1[4*i+0]=v.x; wfc1[4*i+1]=v.y; wfc1[4*i+2]=v.z; wfc1[4*i+3]=v.w;
    }
    const int o2 = j & 15, kc = j >> 4;
    float w2r[8];
#pragma unroll
    for (int i = 0; i < 8; ++i) w2r[i] = fc2_w[o2 * 32 + kc * 8 + i];
    const int dd = j >> 4, kk = j & 15;
    const float w3r = (dd < 3) ? fc3_w[dd * 16 + kk] : 0.0f;
    const float hb1 = fc1_b[o1], hb2 = fc2_b[o2], hb3 = (dd < 3) ? fc3_b[dd] : 0.0f;

    // ---- init ----
    for (int idx = tid; idx < 3 * 8 * 64;   idx += NT) ((float*)s_h)[idx]    = 0.0f;
    for (int idx = tid; idx < 8 * 4 * 2 * 64; idx += NT) ((float*)s_part)[idx] = 0.0f;
    float aih[4];
    {
        const float n0 = noise[(base+q)*3+0], n1 = noise[(base+q)*3+1], n2 = noise[(base+q)*3+2];
#pragma unroll
        for (int gg = 0; gg < 4; ++gg) aih[gg] = wi0[gg][0]*n0 + wi0[gg][1]*n1 + wi0[gg][2]*n2;
    }
    float c0 = 0.0f, c1 = 0.0f, c2 = 0.0f;
    __syncthreads();

    // ---- stage macros ----
#define GEMV2(S0, WI, LX, WH, LH)                                             \
    _Pragma("unroll")                                                         \
    for (int s = (S0); s < (S0) + 4; ++s) {                                   \
        float acc = 0.0f;                                                     \
        const float4* xp = (const float4*)&s_h[LX][s][koff];                  \
        const float4* hp = (const float4*)&s_h[LH][s][koff];                  \
        _Pragma("unroll")                                                     \
        for (int i = 0; i < 8; ++i) {                                         \
            float4 xv = xp[i], hv = hp[i];                                    \
            acc += (WI)[4*i+0]*xv.x + (WI)[4*i+1]*xv.y                        \
                 + (WI)[4*i+2]*xv.z + (WI)[4*i+3]*xv.w;                       \
            acc += (WH)[4*i+0]*hv.x + (WH)[4*i+1]*hv.y                        \
                 + (WH)[4*i+2]*hv.z + (WH)[4*i+3]*hv.w;                       \
        }                                                                     \
        s_part[s][g][kh][j] = acc;                                            \
    }

#define GEMV1(S0, WH, LH)                                                     \
    _Pragma("unroll")                                                         \
    for (int s = (S0); s < (S0) + 4; ++s) {                                   \
        float acc = 0.0f;                                                     \
        const float4* hp = (const float4*)&s_h[LH][s][koff];                  \
        _Pragma("unroll")                                                     \
        for (int i = 0; i < 8; ++i) {                                         \
            float4 hv = hp[i];                                                \
            acc += (WH)[4*i+0]*hv.x + (WH)[4*i+1]*hv.y                        \
                 + (WH)[4*i+2]*hv.z + (WH)[4*i+3]*hv.w;                       \
        }                                                                     \
        s_part[s][g][kh][j] = acc;                                            \
    }

#define GATES(gv)                                                             \
    float gv[4];                                                              \
    _Pragma("unroll")                                                         \
    for (int gg = 0; gg < 4; ++gg)                                            \
        gv[gg] = s_part[q][gg][0][j] + s_part[q][gg][1][j];

#define ACT0_() {                                                             \
        GATES(gv);                                                            \
        float gi = gv[0]+aih[0]+rb0[0], gf = gv[1]+aih[1]+rb0[1];             \
        float gG = gv[2]+aih[2]+rb0[2], go = gv[3]+aih[3]+rb0[3];             \
        c0 = sigm(gf)*c0 + sigm(gi)*tanh_(gG);                                \
        s_h[0][q][j] = sigm(go)*tanh_(c0); }

#define ACT1_() {                                                             \
        GATES(gv);                                                            \
        float gi = gv[0]+rb1v[0], gf = gv[1]+rb1v[1];                         \
        float gG = gv[2]+rb1v[2], go = gv[3]+rb1v[3];                         \
        c1 = sigm(gf)*c1 + sigm(gi)*tanh_(gG);                                \
        s_h[1][q][j] = sigm(go)*tanh_(c1); }

#define ACT2_HEAD(tt) {                                                       \
        GATES(gv);                                                            \
        float gi = gv[0]+rb2v[0], gf = gv[1]+rb2v[1];                         \
        float gG = gv[2]+rb2v[2], go = gv[3]+rb2v[3];                         \
        c2 = sigm(gf)*c2 + sigm(gi)*tanh_(gG);                                \
        s_h[2][q][j] = sigm(go)*tanh_(c2);                                    \
        float acc = 0.0f;                                                     \
        _Pragma("unroll")                                                     \
        for (int i2 = 0; i2 < 8; ++i2) {                                      \
            float4 h4 = *(const float4*)&s_h[2][q][hf*32 + i2*4];             \
            acc += wfc1[4*i2+0]*h4.x + wfc1[4*i2+1]*h4.y                      \
                 + wfc1[4*i2+2]*h4.z + wfc1[4*i2+3]*h4.w;                     \
        }                                                                     \
        acc += __shfl_xor(acc, 32);                                           \
        float y1 = lrelu(acc + hb1);                                          \
        float p2 = 0.0f;                                                      \
        _Pragma("unroll")                                                     \
        for (int i2 = 0; i2 < 8; ++i2) p2 += w2r[i2]*__shfl(y1, kc*8 + i2);   \
        p2 += __shfl_xor(p2, 16); p2 += __shfl_xor(p2, 32);                   \
        float y2 = lrelu(p2 + hb2);                                           \
        float p3 = w3r * __shfl(y2, kk);                                      \
        p3 += __shfl_xor(p3, 1); p3 += __shfl_xor(p3, 2);                     \
        p3 += __shfl_xor(p3, 4); p3 += __shfl_xor(p3, 8);                     \
        float y3 = lrelu(p3 + hb3);                                           \
        if (kk == 0 && dd < 3)                                                \
            out[((size_t)(base + q) * T + (tt)) * 3 + dd] = y3;               \
        float x0 = __shfl(y3, 0), x1 = __shfl(y3, 16), x2 = __shfl(y3, 32);   \
        _Pragma("unroll")                                                     \
        for (int gg = 0; gg < 4; ++gg)                                        \
            aih[gg] = wi0[gg][0]*x0 + wi0[gg][1]*x1 + wi0[gg][2]*x2; }

    // ---- prologue: advance group B (samples 4-7) by half a step ----
    if (q >= 4) ACT0_();                 // h0_B^0 (uses zeroed partials + noise aih)
    __syncthreads();
    GEMV2(4, wi1r, 0, wh1r, 1);          // C(B): gates1_B^0 partials
    __syncthreads();
    if (q >= 4) ACT1_();                 // h1_B^0
    __syncthreads();

    // ---- steady-state: 6 intervals/step, each = serial stage (4 waves) + GEMV (8 waves)
    for (int t = 0; t < T; ++t) {
        // I1: ACT0(A,t)           ||  E(B,t)
        if (q < 4) ACT0_();
        GEMV2(4, wi2r, 1, wh2r, 2);
        __syncthreads();
        // I2: ACT2+head(B,t)      ||  C(A,t)
        if (q >= 4) ACT2_HEAD(t);
        GEMV2(0, wi1r, 0, wh1r, 1);
        __syncthreads();
        // I3: ACT1(A,t)           ||  Ahh(B) for t+1
        if (q < 4) ACT1_();
        GEMV1(4, wh0r, 0);
        __syncthreads();
        // I4: ACT0(B,t+1)         ||  E(A,t)
        if (q >= 4) ACT0_();
        GEMV2(0, wi2r, 1, wh2r, 2);
        __syncthreads();
        // I5: ACT2+head(A,t)      ||  C(B,t+1)
        if (q < 4) ACT2_HEAD(t);
        GEMV2(4, wi1r, 0, wh1r, 1);
        __syncthreads();
        // I6: ACT1(B,t+1)         ||  Ahh(A) for t+1
        if (q >= 4) ACT1_();
        GEMV1(0, wh0r, 0);
        __syncthreads();
    }
    // B's trailing S1-S3 of step T computed in the last iteration are dead state
    // writes (no out stores) — harmless by construction.
}

extern "C" void kernel_launch(void* const* d_in, const int* in_sizes, int n_in,
                              void* d_out, int out_size, void* d_ws, size_t ws_size,
                              hipStream_t stream) {
    const float* noise = (const float*)d_in[0];
    const float* w_ih0 = (const float*)d_in[1];
    const float* w_hh0 = (const float*)d_in[2];
    const float* b_ih0 = (const float*)d_in[3];
    const float* b_hh0 = (const float*)d_in[4];
    const float* w_ih1 = (const float*)d_in[5];
    const float* w_hh1 = (const float*)d_in[6];
    const float* b_ih1 = (const float*)d_in[7];
    const float* b_hh1 = (const float*)d_in[8];
    const float* w_ih2 = (const float*)d_in[9];
    const float* w_hh2 = (const float*)d_in[10];
    const float* b_ih2 = (const float*)d_in[11];
    const float* b_hh2 = (const float*)d_in[12];
    const float* fc1w  = (const float*)d_in[13];
    const float* fc1b  = (const float*)d_in[14];
    const float* fc2w  = (const float*)d_in[15];
    const float* fc2b  = (const float*)d_in[16];
    const float* fc3w  = (const float*)d_in[17];
    const float* fc3b  = (const float*)d_in[18];
    const int*   flp   = (const int*)d_in[19];

    gen_kernel<<<dim3(256), dim3(NT), 0, stream>>>(
        noise, w_ih0, w_hh0, b_ih0, b_hh0,
        w_ih1, w_hh1, b_ih1, b_hh1,
        w_ih2, w_hh2, b_ih2, b_hh2,
        fc1w, fc1b, fc2w, fc2b, fc3w, fc3b,
        flp, (float*)d_out);
}

// Round 7
// 2961.609 us; speedup vs baseline: 1.9426x; 1.9426x over previous
//
#include <hip/hip_runtime.h>

#define NT 512   // 8 waves: wave q = ACT/head sample q; GEMV role = k-slice q (8 halves), 4 gates

typedef _Float16 h2 __attribute__((ext_vector_type(2)));

#if __has_builtin(__builtin_amdgcn_fdot2)
__device__ __forceinline__ float fdot2_(h2 a, h2 b, float c) { return __builtin_amdgcn_fdot2(a, b, c, false); }
#else
__device__ __forceinline__ float fdot2_(h2 a, h2 b, float c) { return c + (float)a.x*(float)b.x + (float)a.y*(float)b.y; }
#endif
#if __has_builtin(__builtin_amdgcn_exp2f)
__device__ __forceinline__ float fexp(float x) { return __builtin_amdgcn_exp2f(x * 1.4426950408889634f); }
#else
__device__ __forceinline__ float fexp(float x) { return __expf(x); }
#endif
#if __has_builtin(__builtin_amdgcn_rcpf)
__device__ __forceinline__ float frcp(float x) { return __builtin_amdgcn_rcpf(x); }
#else
__device__ __forceinline__ float frcp(float x) { return 1.0f / x; }
#endif

__device__ __forceinline__ float sigm(float x)  { return frcp(1.0f + fexp(-x)); }
__device__ __forceinline__ float tanh_(float x) { return 1.0f - 2.0f * frcp(1.0f + fexp(2.0f * x)); }
__device__ __forceinline__ float lrelu(float x) { return x > 0.0f ? x : 0.01f * x; }

// acc over one gate: 4 fdot2 against a float4-packed group of 8 halves
#define DOTG(acc, WP, vv)                                                     \
    acc = fdot2_((WP)[0], __builtin_bit_cast(h2, (vv).x), acc);               \
    acc = fdot2_((WP)[1], __builtin_bit_cast(h2, (vv).y), acc);               \
    acc = fdot2_((WP)[2], __builtin_bit_cast(h2, (vv).z), acc);               \
    acc = fdot2_((WP)[3], __builtin_bit_cast(h2, (vv).w), acc);

__global__ __launch_bounds__(NT, 1)
void gen_kernel(
    const float* __restrict__ noise,
    const float* __restrict__ w_ih0, const float* __restrict__ w_hh0,
    const float* __restrict__ b_ih0, const float* __restrict__ b_hh0,
    const float* __restrict__ w_ih1, const float* __restrict__ w_hh1,
    const float* __restrict__ b_ih1, const float* __restrict__ b_hh1,
    const float* __restrict__ w_ih2, const float* __restrict__ w_hh2,
    const float* __restrict__ b_ih2, const float* __restrict__ b_hh2,
    const float* __restrict__ fc1_w, const float* __restrict__ fc1_b,
    const float* __restrict__ fc2_w, const float* __restrict__ fc2_b,
    const float* __restrict__ fc3_w, const float* __restrict__ fc3_b,
    const int*   __restrict__ flow_len_p,
    float* __restrict__ out)
{
    __shared__ float4    s_part[8][8][64];                                  // 64 KB: [sample][k-slice][unit] -> 4 gate partials (fp32)
    __shared__ _Float16  s_h[3][8][64] __attribute__((aligned(16)));        // 3 KB: h-state fp16

    const int tid  = threadIdx.x;
    const int j    = tid & 63;      // unit / lane
    const int q    = tid >> 6;      // wave: ACT/head sample AND GEMV k-slice
    const int k0   = q * 8;         // k-slice (8 halves = one b128)
    const int base = blockIdx.x * 8;
    const int T    = flow_len_p[0];

    // ---- register-stationary fp16 weights: [gate][k-pair], rows g*64+j, cols [k0,k0+8) ----
    h2 wh0p[4][4], wi1p[4][4], wh1p[4][4], wi2p[4][4], wh2p[4][4];
    float wi0[4][3], rb0[4], rb1v[4], rb2v[4];
#define LWH(dst, src)                                                         \
    { const float4* p4 = (const float4*)((src) + r * 64 + k0);                \
      float4 va = p4[0], vb = p4[1];                                          \
      (dst)[0] = (h2){(_Float16)va.x, (_Float16)va.y};                        \
      (dst)[1] = (h2){(_Float16)va.z, (_Float16)va.w};                        \
      (dst)[2] = (h2){(_Float16)vb.x, (_Float16)vb.y};                        \
      (dst)[3] = (h2){(_Float16)vb.z, (_Float16)vb.w}; }
#pragma unroll
    for (int g = 0; g < 4; ++g) {
        const int r = g * 64 + j;
        LWH(wh0p[g], w_hh0)
        LWH(wi1p[g], w_ih1)
        LWH(wh1p[g], w_hh1)
        LWH(wi2p[g], w_ih2)
        LWH(wh2p[g], w_hh2)
        wi0[g][0] = w_ih0[r*3+0]; wi0[g][1] = w_ih0[r*3+1]; wi0[g][2] = w_ih0[r*3+2];
        rb0[g]  = b_ih0[r] + b_hh0[r];
        rb1v[g] = b_ih1[r] + b_hh1[r];
        rb2v[g] = b_ih2[r] + b_hh2[r];
    }
    // ---- head weights ----
    const int o1 = j & 31, hf = j >> 5;           // fc1: out o1, k-half hf
    h2 wfc1p[16];
#pragma unroll
    for (int i = 0; i < 8; ++i) {
        float4 v = ((const float4*)(fc1_w + o1 * 64 + hf * 32))[i];
        wfc1p[2*i+0] = (h2){(_Float16)v.x, (_Float16)v.y};
        wfc1p[2*i+1] = (h2){(_Float16)v.z, (_Float16)v.w};
    }
    const int o2 = j & 15, kc = j >> 4;           // fc2: out o2, k-chunk kc
    float w2r[8];
#pragma unroll
    for (int i = 0; i < 8; ++i) w2r[i] = fc2_w[o2 * 32 + kc * 8 + i];
    const int dd = j >> 4, kk = j & 15;           // fc3
    const float w3r = (dd < 3) ? fc3_w[dd * 16 + kk] : 0.0f;
    const float hb1 = fc1_b[o1], hb2 = fc2_b[o2], hb3 = (dd < 3) ? fc3_b[dd] : 0.0f;

    // ---- init ----
    for (int idx = tid; idx < 3 * 8 * 64; idx += NT) ((_Float16*)s_h)[idx] = (_Float16)0.0f;
    {
        float4 z = make_float4(0.f, 0.f, 0.f, 0.f);
        float4* pP = (float4*)s_part;
#pragma unroll
        for (int i = 0; i < (8 * 8 * 64) / NT; ++i) pP[tid + i * NT] = z;
    }
    float aih[4];
    {
        const float n0 = noise[(base+q)*3+0], n1 = noise[(base+q)*3+1], n2 = noise[(base+q)*3+2];
#pragma unroll
        for (int g = 0; g < 4; ++g) aih[g] = wi0[g][0]*n0 + wi0[g][1]*n1 + wi0[g][2]*n2;
    }
    float c0 = 0.0f, c1 = 0.0f, c2 = 0.0f;
    __syncthreads();

    // ---- stage macros ----
#define GEMV2(S0, WI, LX, WH, LH)                                             \
    _Pragma("unroll")                                                         \
    for (int s = (S0); s < (S0) + 4; ++s) {                                   \
        const float4 xv = *(const float4*)&s_h[LX][s][k0];                    \
        const float4 hv = *(const float4*)&s_h[LH][s][k0];                    \
        float a0 = 0, a1 = 0, a2 = 0, a3 = 0;                                 \
        DOTG(a0, (WI)[0], xv) DOTG(a0, (WH)[0], hv)                           \
        DOTG(a1, (WI)[1], xv) DOTG(a1, (WH)[1], hv)                           \
        DOTG(a2, (WI)[2], xv) DOTG(a2, (WH)[2], hv)                           \
        DOTG(a3, (WI)[3], xv) DOTG(a3, (WH)[3], hv)                           \
        s_part[s][q][j] = make_float4(a0, a1, a2, a3);                        \
    }

#define GEMV1(S0, WH, LH)                                                     \
    _Pragma("unroll")                                                         \
    for (int s = (S0); s < (S0) + 4; ++s) {                                   \
        const float4 hv = *(const float4*)&s_h[LH][s][k0];                    \
        float a0 = 0, a1 = 0, a2 = 0, a3 = 0;                                 \
        DOTG(a0, (WH)[0], hv)                                                 \
        DOTG(a1, (WH)[1], hv)                                                 \
        DOTG(a2, (WH)[2], hv)                                                 \
        DOTG(a3, (WH)[3], hv)                                                 \
        s_part[s][q][j] = make_float4(a0, a1, a2, a3);                        \
    }

#define GATES(gv)                                                             \
    float4 gv = s_part[q][0][j];                                              \
    _Pragma("unroll")                                                         \
    for (int qq = 1; qq < 8; ++qq) {                                          \
        float4 pp = s_part[q][qq][j];                                         \
        gv.x += pp.x; gv.y += pp.y; gv.z += pp.z; gv.w += pp.w;               \
    }

#define ACT0_() {                                                             \
        GATES(gv);                                                            \
        float gi = gv.x+aih[0]+rb0[0], gf = gv.y+aih[1]+rb0[1];               \
        float gG = gv.z+aih[2]+rb0[2], go = gv.w+aih[3]+rb0[3];               \
        c0 = sigm(gf)*c0 + sigm(gi)*tanh_(gG);                                \
        s_h[0][q][j] = (_Float16)(sigm(go)*tanh_(c0)); }

#define ACT1_() {                                                             \
        GATES(gv);                                                            \
        float gi = gv.x+rb1v[0], gf = gv.y+rb1v[1];                           \
        float gG = gv.z+rb1v[2], go = gv.w+rb1v[3];                           \
        c1 = sigm(gf)*c1 + sigm(gi)*tanh_(gG);                                \
        s_h[1][q][j] = (_Float16)(sigm(go)*tanh_(c1)); }

#define ACT2_HEAD(tt) {                                                       \
        GATES(gv);                                                            \
        float gi = gv.x+rb2v[0], gf = gv.y+rb2v[1];                           \
        float gG = gv.z+rb2v[2], go = gv.w+rb2v[3];                           \
        c2 = sigm(gf)*c2 + sigm(gi)*tanh_(gG);                                \
        s_h[2][q][j] = (_Float16)(sigm(go)*tanh_(c2));                        \
        float acc = 0.0f;                                                     \
        _Pragma("unroll")                                                     \
        for (int i2 = 0; i2 < 4; ++i2) {                                      \
            const float4 hv = *(const float4*)&s_h[2][q][hf*32 + i2*8];       \
            DOTG(acc, (&wfc1p[4*i2]), hv)                                     \
        }                                                                     \
        acc += __shfl_xor(acc, 32);                                           \
        float y1 = lrelu(acc + hb1);                                          \
        float p2 = 0.0f;                                                      \
        _Pragma("unroll")                                                     \
        for (int i2 = 0; i2 < 8; ++i2) p2 += w2r[i2]*__shfl(y1, kc*8 + i2);   \
        p2 += __shfl_xor(p2, 16); p2 += __shfl_xor(p2, 32);                   \
        float y2 = lrelu(p2 + hb2);                                           \
        float p3 = w3r * __shfl(y2, kk);                                      \
        p3 += __shfl_xor(p3, 1); p3 += __shfl_xor(p3, 2);                     \
        p3 += __shfl_xor(p3, 4); p3 += __shfl_xor(p3, 8);                     \
        float y3 = lrelu(p3 + hb3);                                           \
        if (kk == 0 && dd < 3)                                                \
            out[((size_t)(base + q) * T + (tt)) * 3 + dd] = y3;               \
        float x0 = __shfl(y3, 0), x1 = __shfl(y3, 16), x2 = __shfl(y3, 32);   \
        _Pragma("unroll")                                                     \
        for (int g = 0; g < 4; ++g)                                           \
            aih[g] = wi0[g][0]*x0 + wi0[g][1]*x1 + wi0[g][2]*x2; }

    // ---- prologue: advance group B (samples 4-7) by half a step ----
    if (q >= 4) ACT0_();                 // h0_B^0 (zero partials + noise aih)
    __syncthreads();
    GEMV2(4, wi1p, 0, wh1p, 1);          // C(B): gates1_B^0 partials
    __syncthreads();
    if (q >= 4) ACT1_();                 // h1_B^0
    __syncthreads();

    // ---- steady state: 6 intervals/step; each = serial ACT/head (4 waves) || GEMV (all 8 waves)
    for (int t = 0; t < T; ++t) {
        // I1: ACT0(A,t)        || E(B,t)
        if (q < 4) ACT0_();
        GEMV2(4, wi2p, 1, wh2p, 2);
        __syncthreads();
        // I2: ACT2+head(B,t)   || C(A,t)
        if (q >= 4) ACT2_HEAD(t);
        GEMV2(0, wi1p, 0, wh1p, 1);
        __syncthreads();
        // I3: ACT1(A,t)        || Ahh(B) for t+1
        if (q < 4) ACT1_();
        GEMV1(4, wh0p, 0);
        __syncthreads();
        // I4: ACT0(B,t+1)      || E(A,t)
        if (q >= 4) ACT0_();
        GEMV2(0, wi2p, 1, wh2p, 2);
        __syncthreads();
        // I5: ACT2+head(A,t)   || C(B,t+1)
        if (q < 4) ACT2_HEAD(t);
        GEMV2(4, wi1p, 0, wh1p, 1);
        __syncthreads();
        // I6: ACT1(B,t+1)      || Ahh(A) for t+1
        if (q >= 4) ACT1_();
        GEMV1(0, wh0p, 0);
        __syncthreads();
    }
}

extern "C" void kernel_launch(void* const* d_in, const int* in_sizes, int n_in,
                              void* d_out, int out_size, void* d_ws, size_t ws_size,
                              hipStream_t stream) {
    const float* noise = (const float*)d_in[0];
    const float* w_ih0 = (const float*)d_in[1];
    const float* w_hh0 = (const float*)d_in[2];
    const float* b_ih0 = (const float*)d_in[3];
    const float* b_hh0 = (const float*)d_in[4];
    const float* w_ih1 = (const float*)d_in[5];
    const float* w_hh1 = (const float*)d_in[6];
    const float* b_ih1 = (const float*)d_in[7];
    const float* b_hh1 = (const float*)d_in[8];
    const float* w_ih2 = (const float*)d_in[9];
    const float* w_hh2 = (const float*)d_in[10];
    const float* b_ih2 = (const float*)d_in[11];
    const float* b_hh2 = (const float*)d_in[12];
    const float* fc1w  = (const float*)d_in[13];
    const float* fc1b  = (const float*)d_in[14];
    const float* fc2w  = (const float*)d_in[15];
    const float* fc2b  = (const float*)d_in[16];
    const float* fc3w  = (const float*)d_in[17];
    const float* fc3b  = (const float*)d_in[18];
    const int*   flp   = (const int*)d_in[19];

    gen_kernel<<<dim3(256), dim3(NT), 0, stream>>>(
        noise, w_ih0, w_hh0, b_ih0, b_hh0,
        w_ih1, w_hh1, b_ih1, b_hh1,
        w_ih2, w_hh2, b_ih2, b_hh2,
        fc1w, fc1b, fc2w, fc2b, fc3w, fc3b,
        flp, (float*)d_out);
}

// Round 8
// 2273.799 us; speedup vs baseline: 2.5302x; 1.3025x over previous
//
#include <hip/hip_runtime.h>

#define NT 256   // 4 waves; wave q = sample q (ACT/head) + k-slice [16q,16q+16) (GEMV)

typedef _Float16 h2 __attribute__((ext_vector_type(2)));

#if __has_builtin(__builtin_amdgcn_fdot2)
__device__ __forceinline__ float fdot2_(h2 a, h2 b, float c) { return __builtin_amdgcn_fdot2(a, b, c, false); }
#else
__device__ __forceinline__ float fdot2_(h2 a, h2 b, float c) { return c + (float)a.x*(float)b.x + (float)a.y*(float)b.y; }
#endif
#if __has_builtin(__builtin_amdgcn_exp2f)
__device__ __forceinline__ float fexp(float x) { return __builtin_amdgcn_exp2f(x * 1.4426950408889634f); }
#else
__device__ __forceinline__ float fexp(float x) { return __expf(x); }
#endif
#if __has_builtin(__builtin_amdgcn_rcpf)
__device__ __forceinline__ float frcp(float x) { return __builtin_amdgcn_rcpf(x); }
#else
__device__ __forceinline__ float frcp(float x) { return 1.0f / x; }
#endif

__device__ __forceinline__ float sigm(float x)  { return frcp(1.0f + fexp(-x)); }
__device__ __forceinline__ float tanh_(float x) { return 1.0f - 2.0f * frcp(1.0f + fexp(2.0f * x)); }
__device__ __forceinline__ float lrelu(float x) { return x > 0.0f ? x : 0.01f * x; }

// acc += dot8( WP[0..3] (4×h2), vv (float4 = 8 packed halves) )
#define DOTG(acc, WP, vv)                                                     \
    acc = fdot2_((WP)[0], __builtin_bit_cast(h2, (vv).x), acc);               \
    acc = fdot2_((WP)[1], __builtin_bit_cast(h2, (vv).y), acc);               \
    acc = fdot2_((WP)[2], __builtin_bit_cast(h2, (vv).z), acc);               \
    acc = fdot2_((WP)[3], __builtin_bit_cast(h2, (vv).w), acc);

__global__ __launch_bounds__(NT, 2)
void gen_kernel(
    const float* __restrict__ noise,
    const float* __restrict__ w_ih0, const float* __restrict__ w_hh0,
    const float* __restrict__ b_ih0, const float* __restrict__ b_hh0,
    const float* __restrict__ w_ih1, const float* __restrict__ w_hh1,
    const float* __restrict__ b_ih1, const float* __restrict__ b_hh1,
    const float* __restrict__ w_ih2, const float* __restrict__ w_hh2,
    const float* __restrict__ b_ih2, const float* __restrict__ b_hh2,
    const float* __restrict__ fc1_w, const float* __restrict__ fc1_b,
    const float* __restrict__ fc2_w, const float* __restrict__ fc2_b,
    const float* __restrict__ fc3_w, const float* __restrict__ fc3_b,
    const int*   __restrict__ flow_len_p,
    float* __restrict__ out)
{
    __shared__ float4   s_part [4][4][64];                              // 16 KB: C/E partials [sample][slice][unit]
    __shared__ float4   s_part0[4][4][64];                              // 16 KB: layer0 (Ahh) partials
    __shared__ _Float16 s_h[3][4][64] __attribute__((aligned(16)));     // 1.5 KB

    const int tid  = threadIdx.x;
    const int j    = tid & 63;      // unit / lane
    const int q    = tid >> 6;      // wave 0..3: sample q, k-slice q
    const int k0   = q * 16;        // 16 halves = 2 b128 per operand
    const int base = blockIdx.x * 4;
    const int T    = flow_len_p[0];

    // ---- register-stationary fp16 weights: [gate][8×h2], rows g*64+j, cols [k0,k0+16) ----
    h2 wh0p[4][8], wi1p[4][8], wh1p[4][8], wi2p[4][8], wh2p[4][8];
    float wi0[4][3], rb0[4], rb1v[4], rb2v[4];
#define LWH(dst, src)                                                         \
    { const float4* p4 = (const float4*)((src) + r * 64 + k0);                \
      _Pragma("unroll")                                                       \
      for (int i = 0; i < 4; ++i) { float4 v = p4[i];                         \
        (dst)[2*i+0] = (h2){(_Float16)v.x, (_Float16)v.y};                    \
        (dst)[2*i+1] = (h2){(_Float16)v.z, (_Float16)v.w}; } }
#pragma unroll
    for (int g = 0; g < 4; ++g) {
        const int r = g * 64 + j;
        LWH(wh0p[g], w_hh0)
        LWH(wi1p[g], w_ih1)
        LWH(wh1p[g], w_hh1)
        LWH(wi2p[g], w_ih2)
        LWH(wh2p[g], w_hh2)
        wi0[g][0] = w_ih0[r*3+0]; wi0[g][1] = w_ih0[r*3+1]; wi0[g][2] = w_ih0[r*3+2];
        rb0[g]  = b_ih0[r] + b_hh0[r];
        rb1v[g] = b_ih1[r] + b_hh1[r];
        rb2v[g] = b_ih2[r] + b_hh2[r];
    }
    // ---- head weights (wave-local shuffle head, as R7) ----
    const int o1 = j & 31, hf = j >> 5;
    h2 wfc1p[16];
#pragma unroll
    for (int i = 0; i < 8; ++i) {
        float4 v = ((const float4*)(fc1_w + o1 * 64 + hf * 32))[i];
        wfc1p[2*i+0] = (h2){(_Float16)v.x, (_Float16)v.y};
        wfc1p[2*i+1] = (h2){(_Float16)v.z, (_Float16)v.w};
    }
    const int o2 = j & 15, kc = j >> 4;
    float w2r[8];
#pragma unroll
    for (int i = 0; i < 8; ++i) w2r[i] = fc2_w[o2 * 32 + kc * 8 + i];
    const int dd = j >> 4, kk = j & 15;
    const float w3r = (dd < 3) ? fc3_w[dd * 16 + kk] : 0.0f;
    const float hb1 = fc1_b[o1], hb2 = fc2_b[o2], hb3 = (dd < 3) ? fc3_b[dd] : 0.0f;

    // ---- init ----
    for (int idx = tid; idx < 3 * 4 * 64; idx += NT) ((_Float16*)s_h)[idx] = (_Float16)0.0f;
    {
        float4 z = make_float4(0.f, 0.f, 0.f, 0.f);
        float4* pP = (float4*)s_part0;
#pragma unroll
        for (int i = 0; i < (4 * 4 * 64) / NT; ++i) pP[tid + i * NT] = z;
    }
    float aih[4];
    {
        const float n0 = noise[(base+q)*3+0], n1 = noise[(base+q)*3+1], n2 = noise[(base+q)*3+2];
#pragma unroll
        for (int g = 0; g < 4; ++g) aih[g] = wi0[g][0]*n0 + wi0[g][1]*n1 + wi0[g][2]*n2;
    }
    float c0 = 0.0f, c1 = 0.0f, c2 = 0.0f;
    __syncthreads();

    // ---- stage macros ----
#define GEMV2(WI, LX, WH, LH)                                                 \
    _Pragma("unroll")                                                         \
    for (int s = 0; s < 4; ++s) {                                             \
        const float4* xp = (const float4*)&s_h[LX][s][k0];                    \
        const float4* hp = (const float4*)&s_h[LH][s][k0];                    \
        const float4 xv0 = xp[0], xv1 = xp[1];                                \
        const float4 hv0 = hp[0], hv1 = hp[1];                                \
        float a0 = 0, a1 = 0, a2 = 0, a3 = 0;                                 \
        DOTG(a0, &(WI)[0][0], xv0) DOTG(a0, &(WI)[0][4], xv1)                 \
        DOTG(a0, &(WH)[0][0], hv0) DOTG(a0, &(WH)[0][4], hv1)                 \
        DOTG(a1, &(WI)[1][0], xv0) DOTG(a1, &(WI)[1][4], xv1)                 \
        DOTG(a1, &(WH)[1][0], hv0) DOTG(a1, &(WH)[1][4], hv1)                 \
        DOTG(a2, &(WI)[2][0], xv0) DOTG(a2, &(WI)[2][4], xv1)                 \
        DOTG(a2, &(WH)[2][0], hv0) DOTG(a2, &(WH)[2][4], hv1)                 \
        DOTG(a3, &(WI)[3][0], xv0) DOTG(a3, &(WI)[3][4], xv1)                 \
        DOTG(a3, &(WH)[3][0], hv0) DOTG(a3, &(WH)[3][4], hv1)                 \
        s_part[s][q][j] = make_float4(a0, a1, a2, a3);                        \
    }

#define GEMV1_0()                                                             \
    _Pragma("unroll")                                                         \
    for (int s = 0; s < 4; ++s) {                                             \
        const float4* hp = (const float4*)&s_h[0][s][k0];                     \
        const float4 hv0 = hp[0], hv1 = hp[1];                                \
        float a0 = 0, a1 = 0, a2 = 0, a3 = 0;                                 \
        DOTG(a0, &wh0p[0][0], hv0) DOTG(a0, &wh0p[0][4], hv1)                 \
        DOTG(a1, &wh0p[1][0], hv0) DOTG(a1, &wh0p[1][4], hv1)                 \
        DOTG(a2, &wh0p[2][0], hv0) DOTG(a2, &wh0p[2][4], hv1)                 \
        DOTG(a3, &wh0p[3][0], hv0) DOTG(a3, &wh0p[3][4], hv1)                 \
        s_part0[s][q][j] = make_float4(a0, a1, a2, a3);                       \
    }

#define GATES(gv, buf)                                                        \
    float4 gv = buf[q][0][j];                                                 \
    _Pragma("unroll")                                                         \
    for (int qq = 1; qq < 4; ++qq) {                                          \
        float4 pp = buf[q][qq][j];                                            \
        gv.x += pp.x; gv.y += pp.y; gv.z += pp.z; gv.w += pp.w;               \
    }

#define ACT0_() {                                                             \
        GATES(gv, s_part0);                                                   \
        float gi = gv.x+aih[0]+rb0[0], gf = gv.y+aih[1]+rb0[1];               \
        float gG = gv.z+aih[2]+rb0[2], go = gv.w+aih[3]+rb0[3];               \
        c0 = sigm(gf)*c0 + sigm(gi)*tanh_(gG);                                \
        s_h[0][q][j] = (_Float16)(sigm(go)*tanh_(c0)); }

#define ACT1_() {                                                             \
        GATES(gv, s_part);                                                    \
        float gi = gv.x+rb1v[0], gf = gv.y+rb1v[1];                           \
        float gG = gv.z+rb1v[2], go = gv.w+rb1v[3];                           \
        c1 = sigm(gf)*c1 + sigm(gi)*tanh_(gG);                                \
        s_h[1][q][j] = (_Float16)(sigm(go)*tanh_(c1)); }

#define ACT2_() {                                                             \
        GATES(gv, s_part);                                                    \
        float gi = gv.x+rb2v[0], gf = gv.y+rb2v[1];                           \
        float gG = gv.z+rb2v[2], go = gv.w+rb2v[3];                           \
        c2 = sigm(gf)*c2 + sigm(gi)*tanh_(gG);                                \
        s_h[2][q][j] = (_Float16)(sigm(go)*tanh_(c2)); }

#define HEAD(tt) {                                                            \
        float acc = 0.0f;                                                     \
        _Pragma("unroll")                                                     \
        for (int i2 = 0; i2 < 4; ++i2) {                                      \
            const float4 hv = *(const float4*)&s_h[2][q][hf*32 + i2*8];       \
            DOTG(acc, (&wfc1p[4*i2]), hv)                                     \
        }                                                                     \
        acc += __shfl_xor(acc, 32);                                           \
        float y1 = lrelu(acc + hb1);                                          \
        float p2 = 0.0f;                                                      \
        _Pragma("unroll")                                                     \
        for (int i2 = 0; i2 < 8; ++i2) p2 += w2r[i2]*__shfl(y1, kc*8 + i2);   \
        p2 += __shfl_xor(p2, 16); p2 += __shfl_xor(p2, 32);                   \
        float y2 = lrelu(p2 + hb2);                                           \
        float p3 = w3r * __shfl(y2, kk);                                      \
        p3 += __shfl_xor(p3, 1); p3 += __shfl_xor(p3, 2);                     \
        p3 += __shfl_xor(p3, 4); p3 += __shfl_xor(p3, 8);                     \
        float y3 = lrelu(p3 + hb3);                                           \
        if (kk == 0 && dd < 3)                                                \
            out[((size_t)(base + q) * T + (tt)) * 3 + dd] = y3;               \
        float x0 = __shfl(y3, 0), x1 = __shfl(y3, 16), x2 = __shfl(y3, 32);   \
        _Pragma("unroll")                                                     \
        for (int g = 0; g < 4; ++g)                                           \
            aih[g] = wi0[g][0]*x0 + wi0[g][1]*x1 + wi0[g][2]*x2; }

    // ---- time loop: 5 barriers/step; cross-block drift (2 blocks/CU) hides
    //      the serial ACT intervals and barrier drains ----
    for (int t = 0; t < T; ++t) {
        // S1: ACT0 (reads s_part0 from prev step's S5; writes h0^t)
        ACT0_();
        __syncthreads();
        // S2: C — layer1 partials (x=h0^t, h=h1^{t-1})
        GEMV2(wi1p, 0, wh1p, 1);
        __syncthreads();
        // S3: ACT1 (writes h1^t)
        ACT1_();
        __syncthreads();
        // S4: E — layer2 partials (x=h1^t, h=h2^{t-1})
        GEMV2(wi2p, 1, wh2p, 2);
        __syncthreads();
        // S5: ACT2 (h2^t) + Ahh(t+1) into s_part0 + head (shuffle chain
        //     overlapped with Ahh's independent FMA stream)
        ACT2_();
        GEMV1_0();
        HEAD(t);
        __syncthreads();
    }
}

extern "C" void kernel_launch(void* const* d_in, const int* in_sizes, int n_in,
                              void* d_out, int out_size, void* d_ws, size_t ws_size,
                              hipStream_t stream) {
    const float* noise = (const float*)d_in[0];
    const float* w_ih0 = (const float*)d_in[1];
    const float* w_hh0 = (const float*)d_in[2];
    const float* b_ih0 = (const float*)d_in[3];
    const float* b_hh0 = (const float*)d_in[4];
    const float* w_ih1 = (const float*)d_in[5];
    const float* w_hh1 = (const float*)d_in[6];
    const float* b_ih1 = (const float*)d_in[7];
    const float* b_hh1 = (const float*)d_in[8];
    const float* w_ih2 = (const float*)d_in[9];
    const float* w_hh2 = (const float*)d_in[10];
    const float* b_ih2 = (const float*)d_in[11];
    const float* b_hh2 = (const float*)d_in[12];
    const float* fc1w  = (const float*)d_in[13];
    const float* fc1b  = (const float*)d_in[14];
    const float* fc2w  = (const float*)d_in[15];
    const float* fc2b  = (const float*)d_in[16];
    const float* fc3w  = (const float*)d_in[17];
    const float* fc3b  = (const float*)d_in[18];
    const int*   flp   = (const int*)d_in[19];

    gen_kernel<<<dim3(512), dim3(NT), 0, stream>>>(
        noise, w_ih0, w_hh0, b_ih0, b_hh0,
        w_ih1, w_hh1, b_ih1, b_hh1,
        w_ih2, w_hh2, b_ih2, b_hh2,
        fc1w, fc1b, fc2w, fc2b, fc3w, fc3b,
        flp, (float*)d_out);
}

// Round 9
// 975.449 us; speedup vs baseline: 5.8979x; 2.3310x over previous
//
#include <hip/hip_runtime.h>

#define NT 512   // 8 waves; wave w owns gate-tiles {2w,2w+1} = units 8w..8w+7 (all 4 gates)

typedef _Float16 f16x8 __attribute__((ext_vector_type(8)));
typedef _Float16 f16x4 __attribute__((ext_vector_type(4)));
typedef float    f32x4 __attribute__((ext_vector_type(4)));

#define MFMA(a, b, c) __builtin_amdgcn_mfma_f32_16x16x32_f16((a), (b), (c), 0, 0, 0)

#if __has_builtin(__builtin_amdgcn_exp2f)
__device__ __forceinline__ float fexp(float x) { return __builtin_amdgcn_exp2f(x * 1.4426950408889634f); }
#else
__device__ __forceinline__ float fexp(float x) { return __expf(x); }
#endif
#if __has_builtin(__builtin_amdgcn_rcpf)
__device__ __forceinline__ float frcp(float x) { return __builtin_amdgcn_rcpf(x); }
#else
__device__ __forceinline__ float frcp(float x) { return 1.0f / x; }
#endif
__device__ __forceinline__ float sigm(float x)  { return frcp(1.0f + fexp(-x)); }
__device__ __forceinline__ float tanh_(float x) { return 1.0f - 2.0f * frcp(1.0f + fexp(2.0f * x)); }
__device__ __forceinline__ float lrelu(float x) { return x > 0.0f ? x : 0.01f * x; }

// 8 consecutive fp32 -> f16x8 (A-fragment slice)
__device__ __forceinline__ f16x8 ld8(const float* p) {
    const float4* q = (const float4*)p;
    float4 a = q[0], b = q[1];
    f16x8 r = { (_Float16)a.x, (_Float16)a.y, (_Float16)a.z, (_Float16)a.w,
                (_Float16)b.x, (_Float16)b.y, (_Float16)b.z, (_Float16)b.w };
    return r;
}

__global__ __launch_bounds__(NT, 2)
void gen_kernel(
    const float* __restrict__ noise,
    const float* __restrict__ w_ih0, const float* __restrict__ w_hh0,
    const float* __restrict__ b_ih0, const float* __restrict__ b_hh0,
    const float* __restrict__ w_ih1, const float* __restrict__ w_hh1,
    const float* __restrict__ b_ih1, const float* __restrict__ b_hh1,
    const float* __restrict__ w_ih2, const float* __restrict__ w_hh2,
    const float* __restrict__ b_ih2, const float* __restrict__ b_hh2,
    const float* __restrict__ fc1_w, const float* __restrict__ fc1_b,
    const float* __restrict__ fc2_w, const float* __restrict__ fc2_b,
    const float* __restrict__ fc3_w, const float* __restrict__ fc3_b,
    const int*   __restrict__ flow_len_p,
    float* __restrict__ out)
{
    // h-state per layer, double-buffered; [sample][unit], rows padded to 72
    // halves (bank stride 36 dwords -> 2-way = free)
    __shared__ _Float16 sh[3][2][16][72] __attribute__((aligned(16)));
    __shared__ _Float16 sx [16][40] __attribute__((aligned(16)));  // x: [0..2]=y3, [3]=1 (bias), rest 0
    __shared__ _Float16 sy1[16][40] __attribute__((aligned(16)));
    __shared__ _Float16 sy2[16][40] __attribute__((aligned(16)));  // halves 16..31 stay 0 (K-pad)

    const int tid  = threadIdx.x;
    const int l    = tid & 63;
    const int w    = tid >> 6;     // wave 0..7
    const int ls   = l & 15;       // sample col (B/C) == row-in-tile (A)
    const int lj   = l >> 4;       // 0..3
    const int base = blockIdx.x * 8;
    const int T    = flow_len_p[0];

    // ---------- A fragments (weights, fp16, register/AGPR-stationary) ----------
    // Gate-interleaved row space: tile Tg covers rows 16Tg..16Tg+15, row-in-tile
    // rt -> unit 4Tg+(rt>>2), gate rt&3.  A-lane: rt = ls, k-slot = 32kc+8lj+i.
    const int gA   = ls & 3;
    const int rA0  = gA * 64 + 4 * (2 * w + 0) + (ls >> 2);
    const int rA1  = gA * 64 + 4 * (2 * w + 1) + (ls >> 2);

    f16x8 A1[2][4], A2[2][4], A0[2][3];
#pragma unroll
    for (int kc = 0; kc < 2; ++kc) {
        A1[0][kc]     = ld8(w_ih1 + rA0 * 64 + 32 * kc + 8 * lj);
        A1[1][kc]     = ld8(w_ih1 + rA1 * 64 + 32 * kc + 8 * lj);
        A1[0][2 + kc] = ld8(w_hh1 + rA0 * 64 + 32 * kc + 8 * lj);
        A1[1][2 + kc] = ld8(w_hh1 + rA1 * 64 + 32 * kc + 8 * lj);
        A2[0][kc]     = ld8(w_ih2 + rA0 * 64 + 32 * kc + 8 * lj);
        A2[1][kc]     = ld8(w_ih2 + rA1 * 64 + 32 * kc + 8 * lj);
        A2[0][2 + kc] = ld8(w_hh2 + rA0 * 64 + 32 * kc + 8 * lj);
        A2[1][2 + kc] = ld8(w_hh2 + rA1 * 64 + 32 * kc + 8 * lj);
        A0[0][kc]     = ld8(w_hh0 + rA0 * 64 + 32 * kc + 8 * lj);
        A0[1][kc]     = ld8(w_hh0 + rA1 * 64 + 32 * kc + 8 * lj);
    }
    // layer0 extra chunk: k<3 = w_ih0 cols, k==3 = combined bias, else 0
#pragma unroll
    for (int tt = 0; tt < 2; ++tt) {
        const int r = tt ? rA1 : rA0;
        f16x8 v;
#pragma unroll
        for (int i = 0; i < 8; ++i) {
            int kl = 8 * lj + i;
            float x = (kl < 3) ? w_ih0[r * 3 + kl]
                    : (kl == 3) ? (b_ih0[r] + b_hh0[r]) : 0.0f;
            v[i] = (_Float16)x;
        }
        A0[tt][2] = v;
    }
    // head A-frags (natural row order)
    f16x8 F1[2][2], F2, F3;
#pragma unroll
    for (int tt = 0; tt < 2; ++tt)
#pragma unroll
        for (int kc = 0; kc < 2; ++kc)
            F1[tt][kc] = ld8(fc1_w + (16 * tt + ls) * 64 + 32 * kc + 8 * lj);
    F2 = ld8(fc2_w + ls * 32 + 8 * lj);
    {
        f16x8 v;
#pragma unroll
        for (int i = 0; i < 8; ++i) {
            int k = 8 * lj + i;
            v[i] = (_Float16)((ls < 3 && k < 16) ? fc3_w[ls * 16 + k] : 0.0f);
        }
        F3 = v;
    }
    // ACT biases (layers 1,2); C-thread unit = 4*Tg + lj, gate = reg index
    const int uc0 = 8 * w + lj, uc1 = 8 * w + 4 + lj;
    float b1v[2][4], b2v[2][4];
#pragma unroll
    for (int g = 0; g < 4; ++g) {
        b1v[0][g] = b_ih1[g * 64 + uc0] + b_hh1[g * 64 + uc0];
        b1v[1][g] = b_ih1[g * 64 + uc1] + b_hh1[g * 64 + uc1];
        b2v[0][g] = b_ih2[g * 64 + uc0] + b_hh2[g * 64 + uc0];
        b2v[1][g] = b_ih2[g * 64 + uc1] + b_hh2[g * 64 + uc1];
    }
    // head biases (C rows = 4*lj + r)
    float hb1a[4], hb1b[4], hb2[4];
#pragma unroll
    for (int r = 0; r < 4; ++r) {
        hb1a[r] = fc1_b[4 * lj + r];
        hb1b[r] = fc1_b[16 + 4 * lj + r];
        hb2[r]  = fc2_b[4 * lj + r];
    }
    float fb3[3] = { fc3_b[0], fc3_b[1], fc3_b[2] };

    // ---------- LDS init ----------
    for (int i = tid; i < 3 * 2 * 16 * 72; i += NT) ((_Float16*)sh)[i]  = (_Float16)0.0f;
    for (int i = tid; i < 16 * 40; i += NT) {
        ((_Float16*)sx)[i]  = (_Float16)0.0f;
        ((_Float16*)sy1)[i] = (_Float16)0.0f;
        ((_Float16*)sy2)[i] = (_Float16)0.0f;
    }
    __syncthreads();
    if (tid < 16) sx[tid][3] = (_Float16)1.0f;          // bias lane
    if (tid < 24) {                                      // live samples 0..7
        int s = tid / 3, d = tid % 3;
        sx[s][d] = (_Float16)noise[(base + s) * 3 + d];
    }

    float c0[2] = {0, 0}, c1[2] = {0, 0}, c2[2] = {0, 0};
    __syncthreads();

#define RD(L, p, kb) (*(const f16x8*)&sh[L][p][ls][(kb) + 8 * lj])

#define ACT(acc, bv, cref, L, p, u) {                                          \
        float gi = acc[0] + bv[0], gf = acc[1] + bv[1];                        \
        float gg = acc[2] + bv[2], go = acc[3] + bv[3];                        \
        cref = sigm(gf) * cref + sigm(gi) * tanh_(gg);                         \
        sh[L][p][ls][u] = (_Float16)(sigm(go) * tanh_(cref)); }

    // ---------- prologue: h0(0) from noise (h-part is zero) ----------
    {
        f16x8 bx = *(const f16x8*)&sx[ls][8 * lj];
        f32x4 a0 = {0, 0, 0, 0}, a1 = {0, 0, 0, 0};
        a0 = MFMA(A0[0][2], bx, a0);
        a1 = MFMA(A0[1][2], bx, a1);
        float zb[4] = {0, 0, 0, 0};
        ACT(a0, zb, c0[0], 0, 0, uc0)
        ACT(a1, zb, c0[1], 0, 0, uc1)
    }
    __syncthreads();

    // ---------- time loop: 4 barriers/step ----------
    for (int t = 0; t < T; ++t) {
        const int pc = t & 1, pp = pc ^ 1;
        // I1: gates1 = [Wi1|Wh1]·[h0(t); h1(t-1)] -> ACT1 -> h1(t)
        {
            f16x8 q0 = RD(0, pc, 0), q1 = RD(0, pc, 32);
            f16x8 q2 = RD(1, pp, 0), q3 = RD(1, pp, 32);
            f32x4 a0 = {0, 0, 0, 0}, a1 = {0, 0, 0, 0};
            a0 = MFMA(A1[0][0], q0, a0); a1 = MFMA(A1[1][0], q0, a1);
            a0 = MFMA(A1[0][1], q1, a0); a1 = MFMA(A1[1][1], q1, a1);
            a0 = MFMA(A1[0][2], q2, a0); a1 = MFMA(A1[1][2], q2, a1);
            a0 = MFMA(A1[0][3], q3, a0); a1 = MFMA(A1[1][3], q3, a1);
            ACT(a0, b1v[0], c1[0], 1, pc, uc0)
            ACT(a1, b1v[1], c1[1], 1, pc, uc1)
        }
        __syncthreads();
        // I2: gates2 = [Wi2|Wh2]·[h1(t); h2(t-1)] -> ACT2 -> h2(t)
        {
            f16x8 q0 = RD(1, pc, 0), q1 = RD(1, pc, 32);
            f16x8 q2 = RD(2, pp, 0), q3 = RD(2, pp, 32);
            f32x4 a0 = {0, 0, 0, 0}, a1 = {0, 0, 0, 0};
            a0 = MFMA(A2[0][0], q0, a0); a1 = MFMA(A2[1][0], q0, a1);
            a0 = MFMA(A2[0][1], q1, a0); a1 = MFMA(A2[1][1], q1, a1);
            a0 = MFMA(A2[0][2], q2, a0); a1 = MFMA(A2[1][2], q2, a1);
            a0 = MFMA(A2[0][3], q3, a0); a1 = MFMA(A2[1][3], q3, a1);
            ACT(a0, b2v[0], c2[0], 2, pc, uc0)
            ACT(a1, b2v[1], c2[1], 2, pc, uc1)
        }
        __syncthreads();
        // I3: layer0-hh (all waves, acc held to I4)  ||  head on wave 0
        f32x4 h0a = {0, 0, 0, 0}, h0b = {0, 0, 0, 0};
        {
            f16x8 q0 = RD(0, pc, 0), q1 = RD(0, pc, 32);
            h0a = MFMA(A0[0][0], q0, h0a); h0b = MFMA(A0[1][0], q0, h0b);
            h0a = MFMA(A0[0][1], q1, h0a); h0b = MFMA(A0[1][1], q1, h0b);
        }
        if (w == 0) {
            // fc1 (all 32 rows, one wave); wave-synchronous LDS round trips
            f16x8 bh0 = RD(2, pc, 0), bh1 = RD(2, pc, 32);
            f32x4 y1a = {0, 0, 0, 0}, y1b = {0, 0, 0, 0};
            y1a = MFMA(F1[0][0], bh0, y1a); y1b = MFMA(F1[1][0], bh0, y1b);
            y1a = MFMA(F1[0][1], bh1, y1a); y1b = MFMA(F1[1][1], bh1, y1b);
            f16x4 v;
#pragma unroll
            for (int r = 0; r < 4; ++r) v[r] = (_Float16)lrelu(y1a[r] + hb1a[r]);
            *(f16x4*)&sy1[ls][4 * lj] = v;
#pragma unroll
            for (int r = 0; r < 4; ++r) v[r] = (_Float16)lrelu(y1b[r] + hb1b[r]);
            *(f16x4*)&sy1[ls][16 + 4 * lj] = v;
            f16x8 by1 = *(const f16x8*)&sy1[ls][8 * lj];
            f32x4 y2 = {0, 0, 0, 0};
            y2 = MFMA(F2, by1, y2);
#pragma unroll
            for (int r = 0; r < 4; ++r) v[r] = (_Float16)lrelu(y2[r] + hb2[r]);
            *(f16x4*)&sy2[ls][4 * lj] = v;
            f16x8 by2 = *(const f16x8*)&sy2[ls][8 * lj];
            f32x4 y3 = {0, 0, 0, 0};
            y3 = MFMA(F3, by2, y3);
            if (lj == 0) {                       // C rows 0..3 -> d = 0..2
                float o0 = lrelu(y3[0] + fb3[0]);
                float o1 = lrelu(y3[1] + fb3[1]);
                float o2 = lrelu(y3[2] + fb3[2]);
                sx[ls][0] = (_Float16)o0;
                sx[ls][1] = (_Float16)o1;
                sx[ls][2] = (_Float16)o2;
                if (ls < 8) {
                    float* op = out + ((size_t)(base + ls) * T + t) * 3;
                    op[0] = o0; op[1] = o1; op[2] = o2;
                }
            }
        }
        __syncthreads();
        // I4: gates0 += Wi0p·[y3;1;0..] -> ACT0 -> h0(t+1)
        {
            f16x8 bx = *(const f16x8*)&sx[ls][8 * lj];
            h0a = MFMA(A0[0][2], bx, h0a);
            h0b = MFMA(A0[1][2], bx, h0b);
            float zb[4] = {0, 0, 0, 0};
            ACT(h0a, zb, c0[0], 0, pp, uc0)
            ACT(h0b, zb, c0[1], 0, pp, uc1)
        }
        __syncthreads();
    }
}

extern "C" void kernel_launch(void* const* d_in, const int* in_sizes, int n_in,
                              void* d_out, int out_size, void* d_ws, size_t ws_size,
                              hipStream_t stream) {
    const float* noise = (const float*)d_in[0];
    const float* w_ih0 = (const float*)d_in[1];
    const float* w_hh0 = (const float*)d_in[2];
    const float* b_ih0 = (const float*)d_in[3];
    const float* b_hh0 = (const float*)d_in[4];
    const float* w_ih1 = (const float*)d_in[5];
    const float* w_hh1 = (const float*)d_in[6];
    const float* b_ih1 = (const float*)d_in[7];
    const float* b_hh1 = (const float*)d_in[8];
    const float* w_ih2 = (const float*)d_in[9];
    const float* w_hh2 = (const float*)d_in[10];
    const float* b_ih2 = (const float*)d_in[11];
    const float* b_hh2 = (const float*)d_in[12];
    const float* fc1w  = (const float*)d_in[13];
    const float* fc1b  = (const float*)d_in[14];
    const float* fc2w  = (const float*)d_in[15];
    const float* fc2b  = (const float*)d_in[16];
    const float* fc3w  = (const float*)d_in[17];
    const float* fc3b  = (const float*)d_in[18];
    const int*   flp   = (const int*)d_in[19];

    gen_kernel<<<dim3(256), dim3(NT), 0, stream>>>(
        noise, w_ih0, w_hh0, b_ih0, b_hh0,
        w_ih1, w_hh1, b_ih1, b_hh1,
        w_ih2, w_hh2, b_ih2, b_hh2,
        fc1w, fc1b, fc2w, fc2b, fc3w, fc3b,
        flp, (float*)d_out);
}